// Round 2
// baseline (1153.506 us; speedup 1.0000x reference)
//
#include <hip/hip_runtime.h>
#include <hip/hip_bf16.h>
#include <stdint.h>

#define TOKENS 512
#define HDIM   2048
#define IDIM   1408
#define SIDIM  5632
#define NEXP   60
#define TOPK   4
#define NSLOTS (TOKENS*TOPK)   /* 2048 */
#define ROWPAD 64              /* padding rows so tail tiles read valid memory */

typedef __attribute__((ext_vector_type(8))) short bf16x8;
typedef __attribute__((ext_vector_type(4))) float f32x4;

__device__ __forceinline__ short f2bf(float f){
  uint32_t u = __float_as_uint(f);
  u = (u + 0x7fffu + ((u >> 16) & 1u)) >> 16;   // RNE
  return (short)(u & 0xffffu);
}

__device__ __forceinline__ bf16x8 pack8(float4 a, float4 b){
  bf16x8 r;
  r[0]=f2bf(a.x); r[1]=f2bf(a.y); r[2]=f2bf(a.z); r[3]=f2bf(a.w);
  r[4]=f2bf(b.x); r[5]=f2bf(b.y); r[6]=f2bf(b.z); r[7]=f2bf(b.w);
  return r;
}

__device__ __forceinline__ f32x4 zero4(){
  f32x4 z; z[0]=0.f; z[1]=0.f; z[2]=0.f; z[3]=0.f; return z;
}

__device__ __forceinline__ f32x4 mfma16(bf16x8 a, bf16x8 b, f32x4 c){
  return __builtin_amdgcn_mfma_f32_16x16x32_bf16(a, b, c, 0, 0, 0);
}

// ---------------- router: logits -> softmax -> top-4 + shared sigmoid gate ---
__global__ __launch_bounds__(64) void router_kernel(
    const float* __restrict__ x, const float* __restrict__ rw,
    const float* __restrict__ egw, int* __restrict__ topk_idx,
    float* __restrict__ topk_w, float* __restrict__ gates,
    int* __restrict__ counts)
{
  int t = blockIdx.x;
  int lane = threadIdx.x;
  const float* xr = x + (size_t)t*HDIM;
  float xv[HDIM/64];
  #pragma unroll
  for (int i=0;i<HDIM/64;i++) xv[i] = xr[lane + 64*i];

  float mylogit = -1e30f;
  for (int e=0;e<NEXP;e++){
    const float* w = rw + (size_t)e*HDIM;
    float acc = 0.f;
    #pragma unroll
    for (int i=0;i<HDIM/64;i++) acc += xv[i]*w[lane+64*i];
    #pragma unroll
    for (int s=32;s>0;s>>=1) acc += __shfl_xor(acc, s);
    if (lane == e) mylogit = acc;
  }
  { // shared-expert sigmoid gate
    float acc = 0.f;
    #pragma unroll
    for (int i=0;i<HDIM/64;i++) acc += xv[i]*egw[lane+64*i];
    #pragma unroll
    for (int s=32;s>0;s>>=1) acc += __shfl_xor(acc, s);
    if (lane == 0) gates[t] = 1.f/(1.f + __expf(-acc));
  }
  float m = mylogit;
  #pragma unroll
  for (int s=32;s>0;s>>=1) m = fmaxf(m, __shfl_xor(m, s));
  float p = (lane < NEXP) ? __expf(mylogit - m) : 0.f;
  float sum = p;
  #pragma unroll
  for (int s=32;s>0;s>>=1) sum += __shfl_xor(sum, s);
  float prob = p / sum;
  for (int k=0;k<TOPK;k++){
    float v = prob; int idx = lane;
    #pragma unroll
    for (int s=32;s>0;s>>=1){
      float ov = __shfl_xor(v, s); int oi = __shfl_xor(idx, s);
      if (ov > v || (ov == v && oi < idx)){ v = ov; idx = oi; }
    }
    if (lane == 0){
      topk_idx[t*TOPK+k] = idx;
      topk_w[t*TOPK+k]  = v;
      atomicAdd(&counts[idx], 1);
    }
    if (lane == idx) prob = -1e30f;
  }
}

// ---------------- exclusive prefix over 60 counts -----------------------------
__global__ void prefix_kernel(const int* __restrict__ counts, int* __restrict__ offsets)
{
  if (threadIdx.x == 0){
    int acc = 0;
    for (int e=0;e<NEXP;e++){ offsets[e] = acc; acc += counts[e]; }
    offsets[NEXP] = acc;
  }
}

// ---------------- assign slots, gather tokens (bf16), and make xb ------------
__global__ __launch_bounds__(256) void scatter_kernel(
    const float* __restrict__ x, const int* __restrict__ topk_idx,
    const int* __restrict__ offsets, int* __restrict__ fill,
    int* __restrict__ slot_of, __hip_bfloat16* __restrict__ xg,
    __hip_bfloat16* __restrict__ xb)
{
  int t = blockIdx.x, tid = threadIdx.x;
  __shared__ int sl[TOPK];
  if (tid == 0){
    for (int k=0;k<TOPK;k++){
      int e = topk_idx[t*TOPK+k];
      int pos = atomicAdd(&fill[e], 1);
      int s = offsets[e] + pos;
      slot_of[t*TOPK+k] = s;
      sl[k] = s;
    }
  }
  __syncthreads();
  const float4* xr = (const float4*)(x + (size_t)t*HDIM);
  float4 v0 = xr[tid*2], v1 = xr[tid*2+1];
  bf16x8 b = pack8(v0, v1);
  *(bf16x8*)((short*)xb + (size_t)t*HDIM + tid*8) = b;
  #pragma unroll
  for (int k=0;k<TOPK;k++)
    *(bf16x8*)((short*)xg + (size_t)sl[k]*HDIM + tid*8) = b;
}

// ================= software-pipelined GEMM stages ============================
// Stage = 32 k-floats. A loads issued first, W loads last, so the consumer's
// waitcnt for stage S leaves stage S' (issued after) fully in flight.

struct StageGU {
  bf16x8 a[4];
  float4 g0, g1, u0, u1;
};

__device__ __forceinline__ void load_gu(StageGU& S, const short* a0,
                                        const float* wgp, const float* wup,
                                        int k0, int K){
  #pragma unroll
  for (int mf=0; mf<4; mf++)
    S.a[mf] = *(const bf16x8*)(a0 + (size_t)mf*16*K + k0);
  S.g0 = *(const float4*)(wgp + k0);
  S.g1 = *(const float4*)(wgp + k0 + 4);
  S.u0 = *(const float4*)(wup + k0);
  S.u1 = *(const float4*)(wup + k0 + 4);
}

__device__ __forceinline__ void compute_gu(const StageGU& S, f32x4* accg, f32x4* accu){
  bf16x8 bg = pack8(S.g0, S.g1);
  bf16x8 bu = pack8(S.u0, S.u1);
  #pragma unroll
  for (int mf=0; mf<4; mf++){
    accg[mf] = mfma16(S.a[mf], bg, accg[mf]);
    accu[mf] = mfma16(S.a[mf], bu, accu[mf]);
  }
}

struct StageD {
  bf16x8 a[4];
  float4 w0, w1;
};

__device__ __forceinline__ void load_d(StageD& S, const short* a0,
                                       const float* wp, int k0, int K){
  #pragma unroll
  for (int mf=0; mf<4; mf++)
    S.a[mf] = *(const bf16x8*)(a0 + (size_t)mf*16*K + k0);
  S.w0 = *(const float4*)(wp + k0);
  S.w1 = *(const float4*)(wp + k0 + 4);
}

__device__ __forceinline__ void compute_d(const StageD& S, f32x4* acc){
  bf16x8 b = pack8(S.w0, S.w1);
  #pragma unroll
  for (int mf=0; mf<4; mf++)
    acc[mf] = mfma16(S.a[mf], b, acc[mf]);
}

// ---------------- fused gate+up GEMM with silu(g)*u epilogue ------------------
// offsets!=null: expert mode (e = blockIdx.y, rows = packed slots)
// offsets==null: shared mode  (m-tile = blockIdx.y)
__global__ __launch_bounds__(256) void gateup_kernel(
    const float* __restrict__ Wg_base, const float* __restrict__ Wu_base,
    const __hip_bfloat16* __restrict__ A, __hip_bfloat16* __restrict__ out,
    const int* __restrict__ offsets, int K, int NI)
{
  int m_start, m_end;
  const float *Wg = Wg_base, *Wu = Wu_base;
  if (offsets){
    int e = blockIdx.y;
    m_start = offsets[e]; m_end = offsets[e+1];
    size_t wo = (size_t)e * NI * K;
    Wg += wo; Wu += wo;
  } else {
    m_start = blockIdx.y * 64; m_end = m_start + 64;
  }
  if (m_start >= m_end) return;
  int lane = threadIdx.x & 63;
  int wave = threadIdx.x >> 6;
  int c16 = lane & 15, kq = lane >> 4;
  int wrow = blockIdx.x*64 + wave*16 + c16;         // weight row = output col
  const float* wgp = Wg + (size_t)wrow*K + kq*8;
  const float* wup = Wu + (size_t)wrow*K + kq*8;
  const short* As = (const short*)A;

  for (int m0 = m_start; m0 < m_end; m0 += 64){
    int mrem = m_end - m0;
    const short* a0 = As + (size_t)(m0 + c16)*K + kq*8;
    f32x4 accg[4], accu[4];
    #pragma unroll
    for (int i=0;i<4;i++){ accg[i] = zero4(); accu[i] = zero4(); }

    StageGU SA, SB;
    load_gu(SA, a0, wgp, wup, 0, K);
    int k0 = 0;
    for (; k0 + 64 < K; k0 += 64){
      load_gu(SB, a0, wgp, wup, k0 + 32, K);
      compute_gu(SA, accg, accu);
      load_gu(SA, a0, wgp, wup, k0 + 64, K);
      compute_gu(SB, accg, accu);
    }
    load_gu(SB, a0, wgp, wup, K - 32, K);
    compute_gu(SA, accg, accu);
    compute_gu(SB, accg, accu);

    #pragma unroll
    for (int mf=0; mf<4; mf++){
      #pragma unroll
      for (int j=0;j<4;j++){
        int mrow = mf*16 + kq*4 + j;               // D row=(lane>>4)*4+j (+16*mf)
        if (mrow < mrem){
          float g = accg[mf][j], u = accu[mf][j];
          float s = g * u / (1.f + __expf(-g));    // silu(g)*u
          ((short*)out)[(size_t)(m0+mrow)*NI + wrow] = f2bf(s);
        }
      }
    }
  }
}

// ---------------- down-projection GEMM (fp32 out) -----------------------------
__global__ __launch_bounds__(256) void down_kernel(
    const float* __restrict__ W_base, const __hip_bfloat16* __restrict__ A,
    float* __restrict__ out, const int* __restrict__ offsets, int K, int NH)
{
  int m_start, m_end;
  const float* W = W_base;
  if (offsets){
    int e = blockIdx.y;
    m_start = offsets[e]; m_end = offsets[e+1];
    W += (size_t)e * NH * K;
  } else {
    m_start = blockIdx.y * 64; m_end = m_start + 64;
  }
  if (m_start >= m_end) return;
  int lane = threadIdx.x & 63;
  int wave = threadIdx.x >> 6;
  int c16 = lane & 15, kq = lane >> 4;
  int wrow = blockIdx.x*64 + wave*16 + c16;
  const float* wp = W + (size_t)wrow*K + kq*8;
  const short* As = (const short*)A;

  for (int m0 = m_start; m0 < m_end; m0 += 64){
    int mrem = m_end - m0;
    const short* a0 = As + (size_t)(m0 + c16)*K + kq*8;
    f32x4 acc[4];
    #pragma unroll
    for (int i=0;i<4;i++) acc[i] = zero4();

    StageD SA, SB;
    load_d(SA, a0, wp, 0, K);
    int k0 = 0;
    for (; k0 + 64 < K; k0 += 64){
      load_d(SB, a0, wp, k0 + 32, K);
      compute_d(SA, acc);
      load_d(SA, a0, wp, k0 + 64, K);
      compute_d(SB, acc);
    }
    load_d(SB, a0, wp, K - 32, K);
    compute_d(SA, acc);
    compute_d(SB, acc);

    #pragma unroll
    for (int mf=0; mf<4; mf++){
      #pragma unroll
      for (int j=0;j<4;j++){
        int mrow = mf*16 + kq*4 + j;
        if (mrow < mrem)
          out[(size_t)(m0+mrow)*NH + wrow] = acc[mf][j];
      }
    }
  }
}

// ---------------- final combine: sum top-4 weighted + gated shared -----------
__global__ __launch_bounds__(256) void combine_kernel(
    const float* __restrict__ dslot, const float* __restrict__ shdown,
    const int* __restrict__ slot_of, const float* __restrict__ topw,
    const float* __restrict__ gates, float* __restrict__ out)
{
  int t = blockIdx.x, tid = threadIdx.x;
  int4  sl = ((const int4*)slot_of)[t];
  float4 w = ((const float4*)topw)[t];
  float sg = gates[t];
  const float* r0 = dslot + (size_t)sl.x*HDIM;
  const float* r1 = dslot + (size_t)sl.y*HDIM;
  const float* r2 = dslot + (size_t)sl.z*HDIM;
  const float* r3 = dslot + (size_t)sl.w*HDIM;
  const float* rs = shdown + (size_t)t*HDIM;
  float* o = out + (size_t)t*HDIM;
  #pragma unroll
  for (int it=0; it<HDIM/(256*4); ++it){
    int h = (tid + it*256) * 4;
    float4 a0 = *(const float4*)(r0+h);
    float4 a1 = *(const float4*)(r1+h);
    float4 a2 = *(const float4*)(r2+h);
    float4 a3 = *(const float4*)(r3+h);
    float4 as = *(const float4*)(rs+h);
    float4 r;
    r.x = w.x*a0.x + w.y*a1.x + w.z*a2.x + w.w*a3.x + sg*as.x;
    r.y = w.x*a0.y + w.y*a1.y + w.z*a2.y + w.w*a3.y + sg*as.y;
    r.z = w.x*a0.z + w.y*a1.z + w.z*a2.z + w.w*a3.z + sg*as.z;
    r.w = w.x*a0.w + w.y*a1.w + w.z*a2.w + w.w*a3.w + sg*as.w;
    *(float4*)(o+h) = r;
  }
}

extern "C" void kernel_launch(void* const* d_in, const int* in_sizes, int n_in,
                              void* d_out, int out_size, void* d_ws, size_t ws_size,
                              hipStream_t stream)
{
  const float* x         = (const float*)d_in[0];
  const float* router_w  = (const float*)d_in[1];
  const float* gate_w    = (const float*)d_in[2];
  const float* up_w      = (const float*)d_in[3];
  const float* down_w    = (const float*)d_in[4];
  const float* sh_gate_w = (const float*)d_in[5];
  const float* sh_up_w   = (const float*)d_in[6];
  const float* sh_down_w = (const float*)d_in[7];
  const float* eg_w      = (const float*)d_in[8];

  char* p = (char*)d_ws;
  auto alloc = [&](size_t bytes)->char*{
    char* r = p; p += (bytes + 255) & ~(size_t)255; return r;
  };
  int*   counts   = (int*)  alloc(NEXP*4);
  int*   fill     = (int*)  alloc(NEXP*4);
  int*   offsets  = (int*)  alloc((NEXP+1)*4);
  int*   topk_idx = (int*)  alloc(NSLOTS*4);
  float* topk_w   = (float*)alloc(NSLOTS*4);
  int*   slot_of  = (int*)  alloc(NSLOTS*4);
  float* gates    = (float*)alloc(TOKENS*4);
  __hip_bfloat16* xb    = (__hip_bfloat16*)alloc((size_t)TOKENS*HDIM*2);
  __hip_bfloat16* xg    = (__hip_bfloat16*)alloc((size_t)(NSLOTS+ROWPAD)*HDIM*2);
  __hip_bfloat16* act   = (__hip_bfloat16*)alloc((size_t)(NSLOTS+ROWPAD)*IDIM*2);
  __hip_bfloat16* shact = (__hip_bfloat16*)alloc((size_t)TOKENS*SIDIM*2);
  float* dslot  = (float*)alloc((size_t)NSLOTS*HDIM*4);
  float* shdown = (float*)alloc((size_t)TOKENS*HDIM*4);
  if ((size_t)(p - (char*)d_ws) > ws_size) return;  // ws too small: fail loudly

  hipMemsetAsync(counts, 0, NEXP*4, stream);
  hipMemsetAsync(fill,   0, NEXP*4, stream);

  router_kernel <<<TOKENS, 64, 0, stream>>>(x, router_w, eg_w, topk_idx, topk_w, gates, counts);
  prefix_kernel <<<1, 64, 0, stream>>>(counts, offsets);
  scatter_kernel<<<TOKENS, 256, 0, stream>>>(x, topk_idx, offsets, fill, slot_of, xg, xb);

  gateup_kernel<<<dim3(IDIM/64,  NEXP),      256, 0, stream>>>(gate_w,    up_w,    xg,    act,   offsets, HDIM,  IDIM);
  down_kernel  <<<dim3(HDIM/64,  NEXP),      256, 0, stream>>>(down_w,    act,     dslot, offsets, IDIM,  HDIM);
  gateup_kernel<<<dim3(SIDIM/64, TOKENS/64), 256, 0, stream>>>(sh_gate_w, sh_up_w, xb,    shact, nullptr, HDIM,  SIDIM);
  down_kernel  <<<dim3(HDIM/64,  TOKENS/64), 256, 0, stream>>>(sh_down_w, shact,   shdown, nullptr, SIDIM, HDIM);

  combine_kernel<<<TOKENS, 256, 0, stream>>>(dslot, shdown, slot_of, topk_w, gates, (float*)d_out);
}

// Round 3
// 943.846 us; speedup vs baseline: 1.2221x; 1.2221x over previous
//
#include <hip/hip_runtime.h>
#include <hip/hip_bf16.h>
#include <stdint.h>

#define TOKENS 512
#define HDIM   2048
#define IDIM   1408
#define SIDIM  5632
#define NEXP   60
#define TOPK   4
#define NSLOTS (TOKENS*TOPK)   /* 2048 */
#define ROWPAD 64              /* padding rows so tail tiles read valid memory */

typedef __attribute__((ext_vector_type(8))) short bf16x8;
typedef __attribute__((ext_vector_type(4))) float f32x4;

__device__ __forceinline__ short f2bf(float f){
  uint32_t u = __float_as_uint(f);
  u = (u + 0x7fffu + ((u >> 16) & 1u)) >> 16;   // RNE
  return (short)(u & 0xffffu);
}

__device__ __forceinline__ bf16x8 pack8(float4 a, float4 b){
  bf16x8 r;
  r[0]=f2bf(a.x); r[1]=f2bf(a.y); r[2]=f2bf(a.z); r[3]=f2bf(a.w);
  r[4]=f2bf(b.x); r[5]=f2bf(b.y); r[6]=f2bf(b.z); r[7]=f2bf(b.w);
  return r;
}

__device__ __forceinline__ f32x4 zero4(){
  f32x4 z; z[0]=0.f; z[1]=0.f; z[2]=0.f; z[3]=0.f; return z;
}

__device__ __forceinline__ f32x4 mfma16(bf16x8 a, bf16x8 b, f32x4 c){
  return __builtin_amdgcn_mfma_f32_16x16x32_bf16(a, b, c, 0, 0, 0);
}

// ---- async global->LDS stage of a 64row x 64float fp32 tile -----------------
// LDS layout: linear [64 rows][16 units of 16B], but the 16B units within each
// row are ROTATED by (row&15): physical unit pu holds logical unit
// (pu - row)&15. Source address carries the permutation (global src is
// per-lane; LDS dest must stay linear: base + lane*16).  Reader applies the
// same rotation -> ds_read_b128 bank-residue (2kq + c16) mod 8 is uniform
// (8 lanes per 4-bank group) => conflict-free.
__device__ __forceinline__ void stage_tile(const float* __restrict__ W, int K, int k0,
                                           float4* tile, int tid){
  int l = tid & 63, w = tid >> 6;
  #pragma unroll
  for (int i=0;i<4;i++){
    int r  = i*16 + w*4 + (l>>4);
    int lu = ((l & 15) - (r & 15)) & 15;                 // logical unit for this slot
    const float* src = W + (size_t)r*K + k0 + lu*4;
    float4* dst = tile + (size_t)(i*16 + w*4)*16;        // wave-uniform base
    __builtin_amdgcn_global_load_lds(
        (const __attribute__((address_space(1))) void*)src,
        (__attribute__((address_space(3))) void*)dst, 16, 0, 0);
  }
}

// read one lane's B-fragment pair (k 0..31 and 32..63) from a staged tile
__device__ __forceinline__ void read_wfrag(const float4* tile, int r, int kq,
                                           bf16x8& b0, bf16x8& b1){
  int rot = r & 15;
  const float4* row = tile + (size_t)r*16;
  float4 f0 = row[(2*kq     + rot) & 15];
  float4 f1 = row[(2*kq + 1 + rot) & 15];
  float4 f2 = row[(2*kq + 8 + rot) & 15];
  float4 f3 = row[(2*kq + 9 + rot) & 15];
  b0 = pack8(f0, f1);
  b1 = pack8(f2, f3);
}

__device__ __forceinline__ void loadA(bf16x8* av, const short* a0, int k0, int K){
  #pragma unroll
  for (int mf=0; mf<4; mf++){
    av[mf]   = *(const bf16x8*)(a0 + (size_t)mf*16*K + k0);
    av[4+mf] = *(const bf16x8*)(a0 + (size_t)mf*16*K + k0 + 32);
  }
}

// ---------------- router: logits -> softmax -> top-4 + shared sigmoid gate ---
__global__ __launch_bounds__(64) void router_kernel(
    const float* __restrict__ x, const float* __restrict__ rw,
    const float* __restrict__ egw, int* __restrict__ topk_idx,
    float* __restrict__ topk_w, float* __restrict__ gates,
    int* __restrict__ counts)
{
  int t = blockIdx.x;
  int lane = threadIdx.x;
  const float* xr = x + (size_t)t*HDIM;
  float xv[HDIM/64];
  #pragma unroll
  for (int i=0;i<HDIM/64;i++) xv[i] = xr[lane + 64*i];

  float mylogit = -1e30f;
  for (int e=0;e<NEXP;e++){
    const float* w = rw + (size_t)e*HDIM;
    float acc = 0.f;
    #pragma unroll
    for (int i=0;i<HDIM/64;i++) acc += xv[i]*w[lane+64*i];
    #pragma unroll
    for (int s=32;s>0;s>>=1) acc += __shfl_xor(acc, s);
    if (lane == e) mylogit = acc;
  }
  { // shared-expert sigmoid gate
    float acc = 0.f;
    #pragma unroll
    for (int i=0;i<HDIM/64;i++) acc += xv[i]*egw[lane+64*i];
    #pragma unroll
    for (int s=32;s>0;s>>=1) acc += __shfl_xor(acc, s);
    if (lane == 0) gates[t] = 1.f/(1.f + __expf(-acc));
  }
  float m = mylogit;
  #pragma unroll
  for (int s=32;s>0;s>>=1) m = fmaxf(m, __shfl_xor(m, s));
  float p = (lane < NEXP) ? __expf(mylogit - m) : 0.f;
  float sum = p;
  #pragma unroll
  for (int s=32;s>0;s>>=1) sum += __shfl_xor(sum, s);
  float prob = p / sum;
  for (int k=0;k<TOPK;k++){
    float v = prob; int idx = lane;
    #pragma unroll
    for (int s=32;s>0;s>>=1){
      float ov = __shfl_xor(v, s); int oi = __shfl_xor(idx, s);
      if (ov > v || (ov == v && oi < idx)){ v = ov; idx = oi; }
    }
    if (lane == 0){
      topk_idx[t*TOPK+k] = idx;
      topk_w[t*TOPK+k]  = v;
      atomicAdd(&counts[idx], 1);
    }
    if (lane == idx) prob = -1e30f;
  }
}

// ---------------- exclusive prefix over 60 counts -----------------------------
__global__ void prefix_kernel(const int* __restrict__ counts, int* __restrict__ offsets)
{
  if (threadIdx.x == 0){
    int acc = 0;
    for (int e=0;e<NEXP;e++){ offsets[e] = acc; acc += counts[e]; }
    offsets[NEXP] = acc;
  }
}

// ---------------- assign slots, gather tokens (bf16), and make xb ------------
__global__ __launch_bounds__(256) void scatter_kernel(
    const float* __restrict__ x, const int* __restrict__ topk_idx,
    const int* __restrict__ offsets, int* __restrict__ fill,
    int* __restrict__ slot_of, __hip_bfloat16* __restrict__ xg,
    __hip_bfloat16* __restrict__ xb)
{
  int t = blockIdx.x, tid = threadIdx.x;
  __shared__ int sl[TOPK];
  if (tid == 0){
    for (int k=0;k<TOPK;k++){
      int e = topk_idx[t*TOPK+k];
      int pos = atomicAdd(&fill[e], 1);
      int s = offsets[e] + pos;
      slot_of[t*TOPK+k] = s;
      sl[k] = s;
    }
  }
  __syncthreads();
  const float4* xr = (const float4*)(x + (size_t)t*HDIM);
  float4 v0 = xr[tid*2], v1 = xr[tid*2+1];
  bf16x8 b = pack8(v0, v1);
  *(bf16x8*)((short*)xb + (size_t)t*HDIM + tid*8) = b;
  #pragma unroll
  for (int k=0;k<TOPK;k++)
    *(bf16x8*)((short*)xg + (size_t)sl[k]*HDIM + tid*8) = b;
}

// ---------------- fused gate+up GEMM (LDS-staged W) with silu(g)*u -----------
__global__ __launch_bounds__(256) void gateup_kernel(
    const float* __restrict__ Wg_base, const float* __restrict__ Wu_base,
    const __hip_bfloat16* __restrict__ A, __hip_bfloat16* __restrict__ out,
    const int* __restrict__ offsets, int K, int NI)
{
  __shared__ float4 ldsG[2][64*16];   // 2 x 16 KB
  __shared__ float4 ldsU[2][64*16];   // 2 x 16 KB
  int m_start, m_end;
  const float *Wg = Wg_base, *Wu = Wu_base;
  if (offsets){
    int e = blockIdx.y;
    m_start = offsets[e]; m_end = offsets[e+1];
    size_t wo = (size_t)e * NI * K;
    Wg += wo; Wu += wo;
  } else {
    m_start = blockIdx.y * 64; m_end = m_start + 64;
  }
  if (m_start >= m_end) return;
  int tid  = threadIdx.x;
  int lane = tid & 63;
  int wave = tid >> 6;
  int c16 = lane & 15, kq = lane >> 4;
  int wrow = blockIdx.x*64 + wave*16 + c16;          // weight row = output col
  int r    = wave*16 + c16;                          // row within staged tile
  const float* WgT = Wg + (size_t)(blockIdx.x*64)*K; // tile base (row 0)
  const float* WuT = Wu + (size_t)(blockIdx.x*64)*K;
  const short* As = (const short*)A;

  for (int m0 = m_start; m0 < m_end; m0 += 64){
    int mrem = m_end - m0;
    const short* a0 = As + (size_t)(m0 + c16)*K + kq*8;
    f32x4 accg[4], accu[4];
    #pragma unroll
    for (int i=0;i<4;i++){ accg[i] = zero4(); accu[i] = zero4(); }

    bf16x8 avA[8], avB[8];
    stage_tile(WgT, K, 0, &ldsG[0][0], tid);
    stage_tile(WuT, K, 0, &ldsU[0][0], tid);
    loadA(avA, a0, 0, K);
    __syncthreads();                                  // vmcnt(0) drain: buf0 ready

    for (int k0 = 0; k0 < K; k0 += 128){
      // ---- half 1: compute (buf0, avA); prefetch k0+64 -> buf1/avB ----
      stage_tile(WgT, K, k0+64, &ldsG[1][0], tid);
      stage_tile(WuT, K, k0+64, &ldsU[1][0], tid);
      loadA(avB, a0, k0+64, K);
      {
        bf16x8 bg0,bg1,bu0,bu1;
        read_wfrag(&ldsG[0][0], r, kq, bg0, bg1);
        read_wfrag(&ldsU[0][0], r, kq, bu0, bu1);
        #pragma unroll
        for (int mf=0; mf<4; mf++){
          accg[mf] = mfma16(avA[mf],   bg0, accg[mf]);
          accu[mf] = mfma16(avA[mf],   bu0, accu[mf]);
          accg[mf] = mfma16(avA[4+mf], bg1, accg[mf]);
          accu[mf] = mfma16(avA[4+mf], bu1, accu[mf]);
        }
      }
      __syncthreads();                                // buf1 ready, buf0 free
      // ---- half 2: compute (buf1, avB); prefetch k0+128 -> buf0/avA ----
      if (k0 + 128 < K){
        stage_tile(WgT, K, k0+128, &ldsG[0][0], tid);
        stage_tile(WuT, K, k0+128, &ldsU[0][0], tid);
        loadA(avA, a0, k0+128, K);
      }
      {
        bf16x8 bg0,bg1,bu0,bu1;
        read_wfrag(&ldsG[1][0], r, kq, bg0, bg1);
        read_wfrag(&ldsU[1][0], r, kq, bu0, bu1);
        #pragma unroll
        for (int mf=0; mf<4; mf++){
          accg[mf] = mfma16(avB[mf],   bg0, accg[mf]);
          accu[mf] = mfma16(avB[mf],   bu0, accu[mf]);
          accg[mf] = mfma16(avB[4+mf], bg1, accg[mf]);
          accu[mf] = mfma16(avB[4+mf], bu1, accu[mf]);
        }
      }
      __syncthreads();                                // buf0 ready (or drain tail)
    }

    #pragma unroll
    for (int mf=0; mf<4; mf++){
      #pragma unroll
      for (int j=0;j<4;j++){
        int mrow = mf*16 + kq*4 + j;                  // D row=(lane>>4)*4+j (+16*mf)
        if (mrow < mrem){
          float g = accg[mf][j], u = accu[mf][j];
          float s = g * u / (1.f + __expf(-g));       // silu(g)*u
          ((short*)out)[(size_t)(m0+mrow)*NI + wrow] = f2bf(s);
        }
      }
    }
  }
}

// ---------------- down-projection GEMM (LDS-staged W, fp32 out) --------------
__global__ __launch_bounds__(256) void down_kernel(
    const float* __restrict__ W_base, const __hip_bfloat16* __restrict__ A,
    float* __restrict__ out, const int* __restrict__ offsets, int K, int NH)
{
  __shared__ float4 ldsW[2][64*16];   // 2 x 16 KB
  int m_start, m_end;
  const float* W = W_base;
  if (offsets){
    int e = blockIdx.y;
    m_start = offsets[e]; m_end = offsets[e+1];
    W += (size_t)e * NH * K;
  } else {
    m_start = blockIdx.y * 64; m_end = m_start + 64;
  }
  if (m_start >= m_end) return;
  int tid  = threadIdx.x;
  int lane = tid & 63;
  int wave = tid >> 6;
  int c16 = lane & 15, kq = lane >> 4;
  int wrow = blockIdx.x*64 + wave*16 + c16;
  int r    = wave*16 + c16;
  const float* WT = W + (size_t)(blockIdx.x*64)*K;
  const short* As = (const short*)A;

  for (int m0 = m_start; m0 < m_end; m0 += 64){
    int mrem = m_end - m0;
    const short* a0 = As + (size_t)(m0 + c16)*K + kq*8;
    f32x4 acc[4];
    #pragma unroll
    for (int i=0;i<4;i++) acc[i] = zero4();

    bf16x8 avA[8], avB[8];
    stage_tile(WT, K, 0, &ldsW[0][0], tid);
    loadA(avA, a0, 0, K);
    __syncthreads();

    for (int k0 = 0; k0 < K; k0 += 128){
      stage_tile(WT, K, k0+64, &ldsW[1][0], tid);
      loadA(avB, a0, k0+64, K);
      {
        bf16x8 b0,b1;
        read_wfrag(&ldsW[0][0], r, kq, b0, b1);
        #pragma unroll
        for (int mf=0; mf<4; mf++){
          acc[mf] = mfma16(avA[mf],   b0, acc[mf]);
          acc[mf] = mfma16(avA[4+mf], b1, acc[mf]);
        }
      }
      __syncthreads();
      if (k0 + 128 < K){
        stage_tile(WT, K, k0+128, &ldsW[0][0], tid);
        loadA(avA, a0, k0+128, K);
      }
      {
        bf16x8 b0,b1;
        read_wfrag(&ldsW[1][0], r, kq, b0, b1);
        #pragma unroll
        for (int mf=0; mf<4; mf++){
          acc[mf] = mfma16(avB[mf],   b0, acc[mf]);
          acc[mf] = mfma16(avB[4+mf], b1, acc[mf]);
        }
      }
      __syncthreads();
    }

    #pragma unroll
    for (int mf=0; mf<4; mf++){
      #pragma unroll
      for (int j=0;j<4;j++){
        int mrow = mf*16 + kq*4 + j;
        if (mrow < mrem)
          out[(size_t)(m0+mrow)*NH + wrow] = acc[mf][j];
      }
    }
  }
}

// ---------------- final combine: sum top-4 weighted + gated shared -----------
__global__ __launch_bounds__(256) void combine_kernel(
    const float* __restrict__ dslot, const float* __restrict__ shdown,
    const int* __restrict__ slot_of, const float* __restrict__ topw,
    const float* __restrict__ gates, float* __restrict__ out)
{
  int t = blockIdx.x, tid = threadIdx.x;
  int4  sl = ((const int4*)slot_of)[t];
  float4 w = ((const float4*)topw)[t];
  float sg = gates[t];
  const float* r0 = dslot + (size_t)sl.x*HDIM;
  const float* r1 = dslot + (size_t)sl.y*HDIM;
  const float* r2 = dslot + (size_t)sl.z*HDIM;
  const float* r3 = dslot + (size_t)sl.w*HDIM;
  const float* rs = shdown + (size_t)t*HDIM;
  float* o = out + (size_t)t*HDIM;
  #pragma unroll
  for (int it=0; it<HDIM/(256*4); ++it){
    int h = (tid + it*256) * 4;
    float4 a0 = *(const float4*)(r0+h);
    float4 a1 = *(const float4*)(r1+h);
    float4 a2 = *(const float4*)(r2+h);
    float4 a3 = *(const float4*)(r3+h);
    float4 as = *(const float4*)(rs+h);
    float4 r;
    r.x = w.x*a0.x + w.y*a1.x + w.z*a2.x + w.w*a3.x + sg*as.x;
    r.y = w.x*a0.y + w.y*a1.y + w.z*a2.y + w.w*a3.y + sg*as.y;
    r.z = w.x*a0.z + w.y*a1.z + w.z*a2.z + w.w*a3.z + sg*as.z;
    r.w = w.x*a0.w + w.y*a1.w + w.z*a2.w + w.w*a3.w + sg*as.w;
    *(float4*)(o+h) = r;
  }
}

extern "C" void kernel_launch(void* const* d_in, const int* in_sizes, int n_in,
                              void* d_out, int out_size, void* d_ws, size_t ws_size,
                              hipStream_t stream)
{
  const float* x         = (const float*)d_in[0];
  const float* router_w  = (const float*)d_in[1];
  const float* gate_w    = (const float*)d_in[2];
  const float* up_w      = (const float*)d_in[3];
  const float* down_w    = (const float*)d_in[4];
  const float* sh_gate_w = (const float*)d_in[5];
  const float* sh_up_w   = (const float*)d_in[6];
  const float* sh_down_w = (const float*)d_in[7];
  const float* eg_w      = (const float*)d_in[8];

  char* p = (char*)d_ws;
  auto alloc = [&](size_t bytes)->char*{
    char* r = p; p += (bytes + 255) & ~(size_t)255; return r;
  };
  int*   counts   = (int*)  alloc(NEXP*4);
  int*   fill     = (int*)  alloc(NEXP*4);
  int*   offsets  = (int*)  alloc((NEXP+1)*4);
  int*   topk_idx = (int*)  alloc(NSLOTS*4);
  float* topk_w   = (float*)alloc(NSLOTS*4);
  int*   slot_of  = (int*)  alloc(NSLOTS*4);
  float* gates    = (float*)alloc(TOKENS*4);
  __hip_bfloat16* xb    = (__hip_bfloat16*)alloc((size_t)TOKENS*HDIM*2);
  __hip_bfloat16* xg    = (__hip_bfloat16*)alloc((size_t)(NSLOTS+ROWPAD)*HDIM*2);
  __hip_bfloat16* act   = (__hip_bfloat16*)alloc((size_t)(NSLOTS+ROWPAD)*IDIM*2);
  __hip_bfloat16* shact = (__hip_bfloat16*)alloc((size_t)TOKENS*SIDIM*2);
  float* dslot  = (float*)alloc((size_t)NSLOTS*HDIM*4);
  float* shdown = (float*)alloc((size_t)TOKENS*HDIM*4);
  if ((size_t)(p - (char*)d_ws) > ws_size) return;  // ws too small: fail loudly

  hipMemsetAsync(counts, 0, NEXP*4, stream);
  hipMemsetAsync(fill,   0, NEXP*4, stream);

  router_kernel <<<TOKENS, 64, 0, stream>>>(x, router_w, eg_w, topk_idx, topk_w, gates, counts);
  prefix_kernel <<<1, 64, 0, stream>>>(counts, offsets);
  scatter_kernel<<<TOKENS, 256, 0, stream>>>(x, topk_idx, offsets, fill, slot_of, xg, xb);

  gateup_kernel<<<dim3(IDIM/64,  NEXP),      256, 0, stream>>>(gate_w,    up_w,    xg,    act,   offsets, HDIM,  IDIM);
  down_kernel  <<<dim3(HDIM/64,  NEXP),      256, 0, stream>>>(down_w,    act,     dslot, offsets, IDIM,  HDIM);
  gateup_kernel<<<dim3(SIDIM/64, TOKENS/64), 256, 0, stream>>>(sh_gate_w, sh_up_w, xb,    shact, nullptr, HDIM,  SIDIM);
  down_kernel  <<<dim3(HDIM/64,  TOKENS/64), 256, 0, stream>>>(sh_down_w, shact,   shdown, nullptr, SIDIM, HDIM);

  combine_kernel<<<TOKENS, 256, 0, stream>>>(dslot, shdown, slot_of, topk_w, gates, (float*)d_out);
}

// Round 4
// 666.939 us; speedup vs baseline: 1.7296x; 1.4152x over previous
//
#include <hip/hip_runtime.h>
#include <hip/hip_bf16.h>
#include <stdint.h>

#define TOKENS 512
#define HDIM   2048
#define IDIM   1408
#define SIDIM  5632
#define NEXP   60
#define TOPK   4
#define NSLOTS (TOKENS*TOPK)   /* 2048 */
#define ROWPAD 64              /* padding rows so tail tiles read valid memory */

// counted-vmcnt barrier primitives (T3/T4): raw s_barrier, NO vmcnt(0) drain
#define VMWAIT(N) asm volatile("s_waitcnt vmcnt(" #N ")" ::: "memory")
#define SBAR()    asm volatile("s_barrier" ::: "memory")

typedef __attribute__((ext_vector_type(8))) short bf16x8;
typedef __attribute__((ext_vector_type(4))) float f32x4;

__device__ __forceinline__ short f2bf(float f){
  uint32_t u = __float_as_uint(f);
  u = (u + 0x7fffu + ((u >> 16) & 1u)) >> 16;   // RNE
  return (short)(u & 0xffffu);
}

__device__ __forceinline__ bf16x8 pack8(float4 a, float4 b){
  bf16x8 r;
  r[0]=f2bf(a.x); r[1]=f2bf(a.y); r[2]=f2bf(a.z); r[3]=f2bf(a.w);
  r[4]=f2bf(b.x); r[5]=f2bf(b.y); r[6]=f2bf(b.z); r[7]=f2bf(b.w);
  return r;
}

__device__ __forceinline__ bf16x8 as_bf16x8(float4 v){
  union { float4 f; bf16x8 b; } u; u.f = v; return u.b;
}

__device__ __forceinline__ f32x4 zero4(){
  f32x4 z; z[0]=0.f; z[1]=0.f; z[2]=0.f; z[3]=0.f; return z;
}

__device__ __forceinline__ f32x4 mfma16(bf16x8 a, bf16x8 b, f32x4 c){
  return __builtin_amdgcn_mfma_f32_16x16x32_bf16(a, b, c, 0, 0, 0);
}

// ---- async global->LDS stage: 64row x 64float fp32 W-tile -------------------
// LDS [64 rows][16 units of 16B]; units rotated by row&15 (physical pu holds
// logical (pu-row)&15). LDS dest stays linear (HW: uniform base + lane*16);
// the permutation rides on the per-lane GLOBAL src address (rule #21).
__device__ __forceinline__ void stage_w(float4* tile, const float* __restrict__ W,
                                        int K, int k0, int tid){
  int l = tid & 63, wv = tid >> 6;
  #pragma unroll
  for (int i=0;i<4;i++){
    int r  = i*16 + wv*4 + (l>>4);
    int lu = ((l & 15) - (r & 15)) & 15;
    const float* src = W + (size_t)r*K + k0 + lu*4;
    float4* dst = tile + (size_t)(i*16 + wv*4)*16;       // wave-uniform base
    __builtin_amdgcn_global_load_lds(
        (const __attribute__((address_space(1))) void*)src,
        (__attribute__((address_space(3))) void*)dst, 16, 0, 0);
  }
}

// W-frag read: logical units {2kq,2kq+1,2kq+8,2kq+9} rotated by row ->
// bank residue (2kq+c16)&7 uniform (8 lanes per 4-bank group) => conflict-free
__device__ __forceinline__ void read_wfrag(const float4* tile, int r, int kq,
                                           bf16x8& b0, bf16x8& b1){
  int rot = r & 15;
  const float4* row = tile + (size_t)r*16;
  float4 f0 = row[(2*kq     + rot) & 15];
  float4 f1 = row[(2*kq + 1 + rot) & 15];
  float4 f2 = row[(2*kq + 8 + rot) & 15];
  float4 f3 = row[(2*kq + 9 + rot) & 15];
  b0 = pack8(f0, f1);
  b1 = pack8(f2, f3);
}

// ---- async global->LDS stage: 64row x 64 bf16 A-tile ------------------------
// LDS [64 rows][8 units of 16B], rotated by row&7; 2 loads/thread.
__device__ __forceinline__ void stage_a(float4* tile, const short* __restrict__ Arows,
                                        int K, int k0, int tid){
  int l = tid & 63, wv = tid >> 6;
  #pragma unroll
  for (int j=0;j<2;j++){
    int u0 = wv*128 + j*64;
    int u  = u0 + l;
    int row = u >> 3;
    int lu  = ((u & 7) - (row & 7)) & 7;
    const short* src = Arows + (size_t)row*K + k0 + lu*8;
    __builtin_amdgcn_global_load_lds(
        (const __attribute__((address_space(1))) void*)src,
        (__attribute__((address_space(3))) void*)(tile + u0), 16, 0, 0);
  }
}

// A-frag read: row=c16+16mf, logical units kq and kq+4; residue (kq+c16)&7
// uniform => conflict-free.
__device__ __forceinline__ void read_afrag(const float4* tile, int c16, int kq,
                                           bf16x8* av){
  #pragma unroll
  for (int mf=0; mf<4; mf++){
    int row = c16 + 16*mf;
    const float4* rp = tile + (size_t)row*8;
    av[mf]   = as_bf16x8(rp[(kq     + row) & 7]);
    av[4+mf] = as_bf16x8(rp[(kq + 4 + row) & 7]);
  }
}

// XCD-aware block swizzle (T1). expert mode: x-fastest within XCD (A reuse);
// shared mode: y-fastest within XCD (W-tile reuse across m-tiles).
__device__ __forceinline__ void swz_decode(bool expert_mode, int& bx, int& by){
  int bid = blockIdx.y * gridDim.x + blockIdx.x;
  int nb  = gridDim.x * gridDim.y;
  int w_  = ((nb & 7) == 0) ? ((bid & 7) * (nb >> 3) + (bid >> 3)) : bid;
  if (expert_mode){ bx = w_ % gridDim.x; by = w_ / gridDim.x; }
  else            { by = w_ % gridDim.y; bx = w_ / gridDim.y; }
}

// ---------------- router: logits -> softmax -> top-4 + shared sigmoid gate ---
__global__ __launch_bounds__(64) void router_kernel(
    const float* __restrict__ x, const float* __restrict__ rw,
    const float* __restrict__ egw, int* __restrict__ topk_idx,
    float* __restrict__ topk_w, float* __restrict__ gates,
    int* __restrict__ counts)
{
  int t = blockIdx.x;
  int lane = threadIdx.x;
  const float* xr = x + (size_t)t*HDIM;
  float xv[HDIM/64];
  #pragma unroll
  for (int i=0;i<HDIM/64;i++) xv[i] = xr[lane + 64*i];

  float mylogit = -1e30f;
  for (int e=0;e<NEXP;e++){
    const float* w = rw + (size_t)e*HDIM;
    float acc = 0.f;
    #pragma unroll
    for (int i=0;i<HDIM/64;i++) acc += xv[i]*w[lane+64*i];
    #pragma unroll
    for (int s=32;s>0;s>>=1) acc += __shfl_xor(acc, s);
    if (lane == e) mylogit = acc;
  }
  { // shared-expert sigmoid gate
    float acc = 0.f;
    #pragma unroll
    for (int i=0;i<HDIM/64;i++) acc += xv[i]*egw[lane+64*i];
    #pragma unroll
    for (int s=32;s>0;s>>=1) acc += __shfl_xor(acc, s);
    if (lane == 0) gates[t] = 1.f/(1.f + __expf(-acc));
  }
  float m = mylogit;
  #pragma unroll
  for (int s=32;s>0;s>>=1) m = fmaxf(m, __shfl_xor(m, s));
  float p = (lane < NEXP) ? __expf(mylogit - m) : 0.f;
  float sum = p;
  #pragma unroll
  for (int s=32;s>0;s>>=1) sum += __shfl_xor(sum, s);
  float prob = p / sum;
  for (int k=0;k<TOPK;k++){
    float v = prob; int idx = lane;
    #pragma unroll
    for (int s=32;s>0;s>>=1){
      float ov = __shfl_xor(v, s); int oi = __shfl_xor(idx, s);
      if (ov > v || (ov == v && oi < idx)){ v = ov; idx = oi; }
    }
    if (lane == 0){
      topk_idx[t*TOPK+k] = idx;
      topk_w[t*TOPK+k]  = v;
      atomicAdd(&counts[idx], 1);
    }
    if (lane == idx) prob = -1e30f;
  }
}

// ---------------- exclusive prefix over 60 counts -----------------------------
__global__ void prefix_kernel(const int* __restrict__ counts, int* __restrict__ offsets)
{
  if (threadIdx.x == 0){
    int acc = 0;
    for (int e=0;e<NEXP;e++){ offsets[e] = acc; acc += counts[e]; }
    offsets[NEXP] = acc;
  }
}

// ---------------- assign slots, gather tokens (bf16), and make xb ------------
__global__ __launch_bounds__(256) void scatter_kernel(
    const float* __restrict__ x, const int* __restrict__ topk_idx,
    const int* __restrict__ offsets, int* __restrict__ fill,
    int* __restrict__ slot_of, __hip_bfloat16* __restrict__ xg,
    __hip_bfloat16* __restrict__ xb)
{
  int t = blockIdx.x, tid = threadIdx.x;
  __shared__ int sl[TOPK];
  if (tid == 0){
    for (int k=0;k<TOPK;k++){
      int e = topk_idx[t*TOPK+k];
      int pos = atomicAdd(&fill[e], 1);
      int s = offsets[e] + pos;
      slot_of[t*TOPK+k] = s;
      sl[k] = s;
    }
  }
  __syncthreads();
  const float4* xr = (const float4*)(x + (size_t)t*HDIM);
  float4 v0 = xr[tid*2], v1 = xr[tid*2+1];
  bf16x8 b = pack8(v0, v1);
  *(bf16x8*)((short*)xb + (size_t)t*HDIM + tid*8) = b;
  #pragma unroll
  for (int k=0;k<TOPK;k++)
    *(bf16x8*)((short*)xg + (size_t)sl[k]*HDIM + tid*8) = b;
}

// ---------------- fused gate+up GEMM (counted-vmcnt pipeline) ----------------
// LDS (dynamic, 80 KB): G0,G1,U0,U1 (16 KB each) + A0,A1 (8 KB each)
// Per 64-k step, per thread: 4 G + 4 U + 2 A = 10 global_load_lds in flight.
__global__ __launch_bounds__(256) void gateup_kernel(
    const float* __restrict__ Wg_base, const float* __restrict__ Wu_base,
    const __hip_bfloat16* __restrict__ A, __hip_bfloat16* __restrict__ out,
    const int* __restrict__ offsets, int K, int NI)
{
  extern __shared__ __align__(16) char smem[];
  float4* G0 = (float4*)smem;
  float4* G1 = G0 + 1024;
  float4* U0 = G1 + 1024;
  float4* U1 = U0 + 1024;
  float4* A0 = U1 + 1024;
  float4* A1 = A0 + 512;

  int bx, by;
  swz_decode(offsets != nullptr, bx, by);

  int m_start, m_end;
  const float *Wg = Wg_base, *Wu = Wu_base;
  if (offsets){
    m_start = offsets[by]; m_end = offsets[by+1];
    size_t wo = (size_t)by * NI * K;
    Wg += wo; Wu += wo;
  } else {
    m_start = by * 64; m_end = m_start + 64;
  }
  if (m_start >= m_end) return;

  int tid  = threadIdx.x;
  int lane = tid & 63;
  int wv   = tid >> 6;
  int c16 = lane & 15, kq = lane >> 4;
  int wrow = bx*64 + wv*16 + c16;            // weight row = output col
  int r    = wv*16 + c16;                    // row within staged W tile
  const float* WgT = Wg + (size_t)(bx*64)*K;
  const float* WuT = Wu + (size_t)(bx*64)*K;
  const short* As = (const short*)A;

  for (int m0 = m_start; m0 < m_end; m0 += 64){
    int mrem = m_end - m0;
    const short* Ar = As + (size_t)m0*K;
    f32x4 accg[4], accu[4];
    #pragma unroll
    for (int i=0;i<4;i++){ accg[i] = zero4(); accu[i] = zero4(); }

    // prologue: stage k=0 into buf0 (10 loads in flight)
    stage_w(G0, WgT, K, 0, tid);
    stage_w(U0, WuT, K, 0, tid);
    stage_a(A0, Ar,  K, 0, tid);

    for (int k0 = 0; k0 < K; k0 += 128){       // K % 128 == 0 for all shapes
      // ---- phase 1: prefetch k0+64 -> buf1; compute buf0 ----
      stage_w(G1, WgT, K, k0+64, tid);
      stage_w(U1, WuT, K, k0+64, tid);
      stage_a(A1, Ar,  K, k0+64, tid);
      VMWAIT(10); SBAR();                       // buf0 landed; buf1 in flight
      {
        bf16x8 av[8], bg0,bg1,bu0,bu1;
        read_afrag(A0, c16, kq, av);
        read_wfrag(G0, r, kq, bg0, bg1);
        read_wfrag(U0, r, kq, bu0, bu1);
        #pragma unroll
        for (int mf=0; mf<4; mf++){
          accg[mf] = mfma16(av[mf],   bg0, accg[mf]);
          accu[mf] = mfma16(av[mf],   bu0, accu[mf]);
          accg[mf] = mfma16(av[4+mf], bg1, accg[mf]);
          accu[mf] = mfma16(av[4+mf], bu1, accu[mf]);
        }
      }
      SBAR();                                   // all reads of buf0 done
      // ---- phase 2: prefetch k0+128 -> buf0; compute buf1 ----
      if (k0 + 128 < K){
        stage_w(G0, WgT, K, k0+128, tid);
        stage_w(U0, WuT, K, k0+128, tid);
        stage_a(A0, Ar,  K, k0+128, tid);
        VMWAIT(10);
      } else {
        VMWAIT(0);
      }
      SBAR();                                   // buf1 landed
      {
        bf16x8 av[8], bg0,bg1,bu0,bu1;
        read_afrag(A1, c16, kq, av);
        read_wfrag(G1, r, kq, bg0, bg1);
        read_wfrag(U1, r, kq, bu0, bu1);
        #pragma unroll
        for (int mf=0; mf<4; mf++){
          accg[mf] = mfma16(av[mf],   bg0, accg[mf]);
          accu[mf] = mfma16(av[mf],   bu0, accu[mf]);
          accg[mf] = mfma16(av[4+mf], bg1, accg[mf]);
          accu[mf] = mfma16(av[4+mf], bu1, accu[mf]);
        }
      }
      SBAR();                                   // reads of buf1 done
    }

    #pragma unroll
    for (int mf=0; mf<4; mf++){
      #pragma unroll
      for (int j=0;j<4;j++){
        int mrow = mf*16 + kq*4 + j;            // D row=(lane>>4)*4+j (+16*mf)
        if (mrow < mrem){
          float g = accg[mf][j], u = accu[mf][j];
          float s = g * u / (1.f + __expf(-g)); // silu(g)*u
          ((short*)out)[(size_t)(m0+mrow)*NI + wrow] = f2bf(s);
        }
      }
    }
  }
}

// ---------------- down-projection GEMM (counted-vmcnt pipeline, fp32 out) ----
// LDS (dynamic, 48 KB): W0,W1 (16 KB) + A0,A1 (8 KB). 6 loads/thread/step.
__global__ __launch_bounds__(256) void down_kernel(
    const float* __restrict__ W_base, const __hip_bfloat16* __restrict__ A,
    float* __restrict__ out, const int* __restrict__ offsets, int K, int NH)
{
  extern __shared__ __align__(16) char smem[];
  float4* W0 = (float4*)smem;
  float4* W1 = W0 + 1024;
  float4* A0 = W1 + 1024;
  float4* A1 = A0 + 512;

  int bx, by;
  swz_decode(offsets != nullptr, bx, by);

  int m_start, m_end;
  const float* W = W_base;
  if (offsets){
    m_start = offsets[by]; m_end = offsets[by+1];
    W += (size_t)by * NH * K;
  } else {
    m_start = by * 64; m_end = m_start + 64;
  }
  if (m_start >= m_end) return;

  int tid  = threadIdx.x;
  int lane = tid & 63;
  int wv   = tid >> 6;
  int c16 = lane & 15, kq = lane >> 4;
  int wrow = bx*64 + wv*16 + c16;
  int r    = wv*16 + c16;
  const float* WT = W + (size_t)(bx*64)*K;
  const short* As = (const short*)A;

  for (int m0 = m_start; m0 < m_end; m0 += 64){
    int mrem = m_end - m0;
    const short* Ar = As + (size_t)m0*K;
    f32x4 acc[4];
    #pragma unroll
    for (int i=0;i<4;i++) acc[i] = zero4();

    stage_w(W0, WT, K, 0, tid);
    stage_a(A0, Ar, K, 0, tid);

    for (int k0 = 0; k0 < K; k0 += 128){
      stage_w(W1, WT, K, k0+64, tid);
      stage_a(A1, Ar, K, k0+64, tid);
      VMWAIT(6); SBAR();
      {
        bf16x8 av[8], b0,b1;
        read_afrag(A0, c16, kq, av);
        read_wfrag(W0, r, kq, b0, b1);
        #pragma unroll
        for (int mf=0; mf<4; mf++){
          acc[mf] = mfma16(av[mf],   b0, acc[mf]);
          acc[mf] = mfma16(av[4+mf], b1, acc[mf]);
        }
      }
      SBAR();
      if (k0 + 128 < K){
        stage_w(W0, WT, K, k0+128, tid);
        stage_a(A0, Ar, K, k0+128, tid);
        VMWAIT(6);
      } else {
        VMWAIT(0);
      }
      SBAR();
      {
        bf16x8 av[8], b0,b1;
        read_afrag(A1, c16, kq, av);
        read_wfrag(W1, r, kq, b0, b1);
        #pragma unroll
        for (int mf=0; mf<4; mf++){
          acc[mf] = mfma16(av[mf],   b0, acc[mf]);
          acc[mf] = mfma16(av[4+mf], b1, acc[mf]);
        }
      }
      SBAR();
    }

    #pragma unroll
    for (int mf=0; mf<4; mf++){
      #pragma unroll
      for (int j=0;j<4;j++){
        int mrow = mf*16 + kq*4 + j;
        if (mrow < mrem)
          out[(size_t)(m0+mrow)*NH + wrow] = acc[mf][j];
      }
    }
  }
}

// ---------------- final combine: sum top-4 weighted + gated shared -----------
__global__ __launch_bounds__(256) void combine_kernel(
    const float* __restrict__ dslot, const float* __restrict__ shdown,
    const int* __restrict__ slot_of, const float* __restrict__ topw,
    const float* __restrict__ gates, float* __restrict__ out)
{
  int t = blockIdx.x, tid = threadIdx.x;
  int4  sl = ((const int4*)slot_of)[t];
  float4 w = ((const float4*)topw)[t];
  float sg = gates[t];
  const float* r0 = dslot + (size_t)sl.x*HDIM;
  const float* r1 = dslot + (size_t)sl.y*HDIM;
  const float* r2 = dslot + (size_t)sl.z*HDIM;
  const float* r3 = dslot + (size_t)sl.w*HDIM;
  const float* rs = shdown + (size_t)t*HDIM;
  float* o = out + (size_t)t*HDIM;
  #pragma unroll
  for (int it=0; it<HDIM/(256*4); ++it){
    int h = (tid + it*256) * 4;
    float4 a0 = *(const float4*)(r0+h);
    float4 a1 = *(const float4*)(r1+h);
    float4 a2 = *(const float4*)(r2+h);
    float4 a3 = *(const float4*)(r3+h);
    float4 as = *(const float4*)(rs+h);
    float4 r;
    r.x = w.x*a0.x + w.y*a1.x + w.z*a2.x + w.w*a3.x + sg*as.x;
    r.y = w.x*a0.y + w.y*a1.y + w.z*a2.y + w.w*a3.y + sg*as.y;
    r.z = w.x*a0.z + w.y*a1.z + w.z*a2.z + w.w*a3.z + sg*as.z;
    r.w = w.x*a0.w + w.y*a1.w + w.z*a2.w + w.w*a3.w + sg*as.w;
    *(float4*)(o+h) = r;
  }
}

extern "C" void kernel_launch(void* const* d_in, const int* in_sizes, int n_in,
                              void* d_out, int out_size, void* d_ws, size_t ws_size,
                              hipStream_t stream)
{
  const float* x         = (const float*)d_in[0];
  const float* router_w  = (const float*)d_in[1];
  const float* gate_w    = (const float*)d_in[2];
  const float* up_w      = (const float*)d_in[3];
  const float* down_w    = (const float*)d_in[4];
  const float* sh_gate_w = (const float*)d_in[5];
  const float* sh_up_w   = (const float*)d_in[6];
  const float* sh_down_w = (const float*)d_in[7];
  const float* eg_w      = (const float*)d_in[8];

  char* p = (char*)d_ws;
  auto alloc = [&](size_t bytes)->char*{
    char* r = p; p += (bytes + 255) & ~(size_t)255; return r;
  };
  int*   counts   = (int*)  alloc(NEXP*4);
  int*   fill     = (int*)  alloc(NEXP*4);
  int*   offsets  = (int*)  alloc((NEXP+1)*4);
  int*   topk_idx = (int*)  alloc(NSLOTS*4);
  float* topk_w   = (float*)alloc(NSLOTS*4);
  int*   slot_of  = (int*)  alloc(NSLOTS*4);
  float* gates    = (float*)alloc(TOKENS*4);
  __hip_bfloat16* xb    = (__hip_bfloat16*)alloc((size_t)TOKENS*HDIM*2);
  __hip_bfloat16* xg    = (__hip_bfloat16*)alloc((size_t)(NSLOTS+ROWPAD)*HDIM*2);
  __hip_bfloat16* act   = (__hip_bfloat16*)alloc((size_t)(NSLOTS+ROWPAD)*IDIM*2);
  __hip_bfloat16* shact = (__hip_bfloat16*)alloc((size_t)TOKENS*SIDIM*2);
  float* dslot  = (float*)alloc((size_t)NSLOTS*HDIM*4);
  float* shdown = (float*)alloc((size_t)TOKENS*HDIM*4);
  if ((size_t)(p - (char*)d_ws) > ws_size) return;  // ws too small: fail loudly

  hipMemsetAsync(counts, 0, NEXP*4, stream);
  hipMemsetAsync(fill,   0, NEXP*4, stream);

  router_kernel <<<TOKENS, 64, 0, stream>>>(x, router_w, eg_w, topk_idx, topk_w, gates, counts);
  prefix_kernel <<<1, 64, 0, stream>>>(counts, offsets);
  scatter_kernel<<<TOKENS, 256, 0, stream>>>(x, topk_idx, offsets, fill, slot_of, xg, xb);

  gateup_kernel<<<dim3(IDIM/64,  NEXP),     256, 80*1024, stream>>>(gate_w,    up_w,    xg,    act,   offsets, HDIM,  IDIM);
  down_kernel  <<<dim3(HDIM/64,  NEXP),     256, 48*1024, stream>>>(down_w,    act,     dslot, offsets, IDIM,  HDIM);
  gateup_kernel<<<dim3(SIDIM/64, TOKENS/64),256, 80*1024, stream>>>(sh_gate_w, sh_up_w, xb,    shact, nullptr, HDIM,  SIDIM);
  down_kernel  <<<dim3(HDIM/64,  TOKENS/64),256, 48*1024, stream>>>(sh_down_w, shact,   shdown, nullptr, SIDIM, HDIM);

  combine_kernel<<<TOKENS, 256, 0, stream>>>(dslot, shdown, slot_of, topk_w, gates, (float*)d_out);
}

// Round 5
// 654.139 us; speedup vs baseline: 1.7634x; 1.0196x over previous
//
#include <hip/hip_runtime.h>
#include <hip/hip_bf16.h>
#include <stdint.h>

#define TOKENS 512
#define HDIM   2048
#define IDIM   1408
#define SIDIM  5632
#define NEXP   60
#define TOPK   4
#define NSLOTS (TOKENS*TOPK)   /* 2048 */
#define ROWPAD 64

// counted-vmcnt barrier primitives (T3/T4): raw s_barrier, NO vmcnt(0) drain
#define VMWAIT(N) asm volatile("s_waitcnt vmcnt(" #N ")" ::: "memory")
#define SBAR()    asm volatile("s_barrier" ::: "memory")

typedef __attribute__((ext_vector_type(8))) short bf16x8;
typedef __attribute__((ext_vector_type(4))) float f32x4;

__device__ __forceinline__ short f2bf(float f){
  uint32_t u = __float_as_uint(f);
  u = (u + 0x7fffu + ((u >> 16) & 1u)) >> 16;   // RNE
  return (short)(u & 0xffffu);
}

__device__ __forceinline__ bf16x8 pack8(float4 a, float4 b){
  bf16x8 r;
  r[0]=f2bf(a.x); r[1]=f2bf(a.y); r[2]=f2bf(a.z); r[3]=f2bf(a.w);
  r[4]=f2bf(b.x); r[5]=f2bf(b.y); r[6]=f2bf(b.z); r[7]=f2bf(b.w);
  return r;
}

__device__ __forceinline__ bf16x8 as_bf16x8(float4 v){
  union { float4 f; bf16x8 b; } u; u.f = v; return u.b;
}

__device__ __forceinline__ f32x4 zero4(){
  f32x4 z; z[0]=0.f; z[1]=0.f; z[2]=0.f; z[3]=0.f; return z;
}

__device__ __forceinline__ f32x4 mfma16(bf16x8 a, bf16x8 b, f32x4 c){
  return __builtin_amdgcn_mfma_f32_16x16x32_bf16(a, b, c, 0, 0, 0);
}

// ================== K-step-32 staged tiles (rule #21 both-sides swizzle) =====
// W tile: 64 rows x 32 fp32 = 8 KB = [64][8] float4 units, units rotated by
// row&7 (physical pu holds logical (pu-row)&7). LDS dest linear (HW), the
// permutation rides on the per-lane GLOBAL src. 2 loads/thread.
__device__ __forceinline__ void stage_w32(float4* tile, const float* __restrict__ W,
                                          int K, int k0, int tid){
  int l = tid & 63, wv = tid >> 6;
  #pragma unroll
  for (int j=0;j<2;j++){
    int u0 = j*256 + wv*64;                 // wave-uniform
    int u  = u0 + l;
    int row = u >> 3;
    int lu  = ((u & 7) - (row & 7)) & 7;
    const float* src = W + (size_t)row*K + k0 + lu*4;
    __builtin_amdgcn_global_load_lds(
        (const __attribute__((address_space(1))) void*)src,
        (__attribute__((address_space(3))) void*)(tile + u0), 16, 0, 0);
  }
}

// one B-fragment (8 bf16 = k kq*8..+8 of row r)
__device__ __forceinline__ bf16x8 read_wfrag32(const float4* tile, int r, int kq){
  int rot = r & 7;
  const float4* row = tile + (size_t)r*8;
  float4 f0 = row[(2*kq     + rot) & 7];
  float4 f1 = row[(2*kq + 1 + rot) & 7];
  return pack8(f0, f1);
}

// A tile: 64 rows x 32 bf16 = 4 KB = [64][4] float4 units, rotated by row&3.
// 1 load/thread.
__device__ __forceinline__ void stage_a32(float4* tile, const short* __restrict__ Arows,
                                          int K, int k0, int tid){
  int l = tid & 63, wv = tid >> 6;
  int u0 = wv*64;
  int u  = u0 + l;
  int row = u >> 2;
  int lu  = ((u & 3) - (row & 3)) & 3;
  const short* src = Arows + (size_t)row*K + k0 + lu*8;
  __builtin_amdgcn_global_load_lds(
      (const __attribute__((address_space(1))) void*)src,
      (__attribute__((address_space(3))) void*)(tile + u0), 16, 0, 0);
}

__device__ __forceinline__ void read_afrag32(const float4* tile, int c16, int kq,
                                             bf16x8* av){
  #pragma unroll
  for (int mf=0; mf<4; mf++){
    int row = c16 + 16*mf;
    av[mf] = as_bf16x8(tile[(size_t)row*4 + ((kq + row) & 3)]);
  }
}

// ---------------- router ------------------------------------------------------
__global__ __launch_bounds__(64) void router_kernel(
    const float* __restrict__ x, const float* __restrict__ rw,
    const float* __restrict__ egw, int* __restrict__ topk_idx,
    float* __restrict__ topk_w, float* __restrict__ gates,
    int* __restrict__ counts)
{
  int t = blockIdx.x;
  int lane = threadIdx.x;
  const float* xr = x + (size_t)t*HDIM;
  float xv[HDIM/64];
  #pragma unroll
  for (int i=0;i<HDIM/64;i++) xv[i] = xr[lane + 64*i];

  float mylogit = -1e30f;
  for (int e=0;e<NEXP;e++){
    const float* w = rw + (size_t)e*HDIM;
    float acc = 0.f;
    #pragma unroll
    for (int i=0;i<HDIM/64;i++) acc += xv[i]*w[lane+64*i];
    #pragma unroll
    for (int s=32;s>0;s>>=1) acc += __shfl_xor(acc, s);
    if (lane == e) mylogit = acc;
  }
  {
    float acc = 0.f;
    #pragma unroll
    for (int i=0;i<HDIM/64;i++) acc += xv[i]*egw[lane+64*i];
    #pragma unroll
    for (int s=32;s>0;s>>=1) acc += __shfl_xor(acc, s);
    if (lane == 0) gates[t] = 1.f/(1.f + __expf(-acc));
  }
  float m = mylogit;
  #pragma unroll
  for (int s=32;s>0;s>>=1) m = fmaxf(m, __shfl_xor(m, s));
  float p = (lane < NEXP) ? __expf(mylogit - m) : 0.f;
  float sum = p;
  #pragma unroll
  for (int s=32;s>0;s>>=1) sum += __shfl_xor(sum, s);
  float prob = p / sum;
  for (int k=0;k<TOPK;k++){
    float v = prob; int idx = lane;
    #pragma unroll
    for (int s=32;s>0;s>>=1){
      float ov = __shfl_xor(v, s); int oi = __shfl_xor(idx, s);
      if (ov > v || (ov == v && oi < idx)){ v = ov; idx = oi; }
    }
    if (lane == 0){
      topk_idx[t*TOPK+k] = idx;
      topk_w[t*TOPK+k]  = v;
      atomicAdd(&counts[idx], 1);
    }
    if (lane == idx) prob = -1e30f;
  }
}

__global__ void prefix_kernel(const int* __restrict__ counts, int* __restrict__ offsets)
{
  if (threadIdx.x == 0){
    int acc = 0;
    for (int e=0;e<NEXP;e++){ offsets[e] = acc; acc += counts[e]; }
    offsets[NEXP] = acc;
  }
}

__global__ __launch_bounds__(256) void scatter_kernel(
    const float* __restrict__ x, const int* __restrict__ topk_idx,
    const int* __restrict__ offsets, int* __restrict__ fill,
    int* __restrict__ slot_of, __hip_bfloat16* __restrict__ xg,
    __hip_bfloat16* __restrict__ xb)
{
  int t = blockIdx.x, tid = threadIdx.x;
  __shared__ int sl[TOPK];
  if (tid == 0){
    for (int k=0;k<TOPK;k++){
      int e = topk_idx[t*TOPK+k];
      int pos = atomicAdd(&fill[e], 1);
      int s = offsets[e] + pos;
      slot_of[t*TOPK+k] = s;
      sl[k] = s;
    }
  }
  __syncthreads();
  const float4* xr = (const float4*)(x + (size_t)t*HDIM);
  float4 v0 = xr[tid*2], v1 = xr[tid*2+1];
  bf16x8 b = pack8(v0, v1);
  *(bf16x8*)((short*)xb + (size_t)t*HDIM + tid*8) = b;
  #pragma unroll
  for (int k=0;k<TOPK;k++)
    *(bf16x8*)((short*)xg + (size_t)sl[k]*HDIM + tid*8) = b;
}

// =============== combined gate+up GEMM (expert + shared in one grid) =========
// grid = 2024 blocks (8 XCDs x 253). per-XCD: pos<88 -> shared (by=xcd),
// else expert q = xcd*165 + pos-88, e=q/22, bx=q%22 (same-expert contiguous).
// LDS 40 KB: G0,G1,U0,U1 (8 KB) + A0,A1 (4 KB) -> 4 blocks/CU.
// 5 global_load_lds per thread per 32-k phase -> VMWAIT(5).
__global__ __launch_bounds__(256, 4) void gateup_all(
    const float* __restrict__ gW_e, const float* __restrict__ uW_e,
    const __hip_bfloat16* __restrict__ A_e, __hip_bfloat16* __restrict__ out_e,
    const float* __restrict__ gW_s, const float* __restrict__ uW_s,
    const __hip_bfloat16* __restrict__ A_s, __hip_bfloat16* __restrict__ out_s,
    const int* __restrict__ offsets)
{
  extern __shared__ __align__(16) char smem[];
  float4* G0 = (float4*)smem;
  float4* G1 = G0 + 512;
  float4* U0 = G1 + 512;
  float4* U1 = U0 + 512;
  float4* A0 = U1 + 512;
  float4* A1 = A0 + 256;

  int bid = blockIdx.x;
  int xcd = bid & 7, pos = bid >> 3;
  const float *Wg, *Wu; const short *Abase; short *outp;
  int NI, bx, m_start, m_end;
  if (pos < 88){                       // shared expert
    bx = pos;
    Wg = gW_s; Wu = uW_s; Abase = (const short*)A_s; outp = (short*)out_s;
    NI = SIDIM;
    m_start = xcd*64; m_end = m_start + 64;
  } else {                             // routed experts
    int q = xcd*165 + (pos - 88);
    int e = q/22; bx = q - e*22;
    size_t wo = (size_t)e * IDIM * HDIM;
    Wg = gW_e + wo; Wu = uW_e + wo;
    Abase = (const short*)A_e; outp = (short*)out_e;
    NI = IDIM;
    m_start = offsets[e]; m_end = offsets[e+1];
  }
  if (m_start >= m_end) return;
  const int K = HDIM;

  int tid  = threadIdx.x;
  int lane = tid & 63;
  int wv   = tid >> 6;
  int c16 = lane & 15, kq = lane >> 4;
  int wrow = bx*64 + wv*16 + c16;
  int r    = wv*16 + c16;
  const float* WgT = Wg + (size_t)(bx*64)*K;
  const float* WuT = Wu + (size_t)(bx*64)*K;

  for (int m0 = m_start; m0 < m_end; m0 += 64){
    int mrem = m_end - m0;
    const short* Ar = Abase + (size_t)m0*K;
    f32x4 accg[4], accu[4];
    #pragma unroll
    for (int i=0;i<4;i++){ accg[i] = zero4(); accu[i] = zero4(); }

    stage_w32(G0, WgT, K, 0, tid);
    stage_w32(U0, WuT, K, 0, tid);
    stage_a32(A0, Ar,  K, 0, tid);

    for (int k0 = 0; k0 < K; k0 += 64){
      stage_w32(G1, WgT, K, k0+32, tid);
      stage_w32(U1, WuT, K, k0+32, tid);
      stage_a32(A1, Ar,  K, k0+32, tid);
      VMWAIT(5); SBAR();
      {
        bf16x8 av[4];
        read_afrag32(A0, c16, kq, av);
        bf16x8 bg = read_wfrag32(G0, r, kq);
        bf16x8 bu = read_wfrag32(U0, r, kq);
        #pragma unroll
        for (int mf=0; mf<4; mf++){
          accg[mf] = mfma16(av[mf], bg, accg[mf]);
          accu[mf] = mfma16(av[mf], bu, accu[mf]);
        }
      }
      SBAR();
      if (k0 + 64 < K){
        stage_w32(G0, WgT, K, k0+64, tid);
        stage_w32(U0, WuT, K, k0+64, tid);
        stage_a32(A0, Ar,  K, k0+64, tid);
        VMWAIT(5);
      } else {
        VMWAIT(0);
      }
      SBAR();
      {
        bf16x8 av[4];
        read_afrag32(A1, c16, kq, av);
        bf16x8 bg = read_wfrag32(G1, r, kq);
        bf16x8 bu = read_wfrag32(U1, r, kq);
        #pragma unroll
        for (int mf=0; mf<4; mf++){
          accg[mf] = mfma16(av[mf], bg, accg[mf]);
          accu[mf] = mfma16(av[mf], bu, accu[mf]);
        }
      }
      SBAR();
    }

    #pragma unroll
    for (int mf=0; mf<4; mf++){
      #pragma unroll
      for (int j=0;j<4;j++){
        int mrow = mf*16 + kq*4 + j;
        if (mrow < mrem){
          float g = accg[mf][j], u = accu[mf][j];
          float s = g * u / (1.f + __expf(-g));
          outp[(size_t)(m0+mrow)*NI + wrow] = f2bf(s);
        }
      }
    }
  }
}

// =============== combined down GEMM (expert + shared in one grid) ============
// grid = 2176 blocks (8 x 272). per-XCD: pos<32 -> shared (by=xcd, K=SIDIM,
// 4x longer -> dispatched first), else expert q = xcd*240+pos-32, e=q/32.
// LDS 24 KB: W0,W1 (8 KB) + A0,A1 (4 KB). 3 loads/thread/phase -> VMWAIT(3).
__global__ __launch_bounds__(256, 4) void down_all(
    const float* __restrict__ W_e, const __hip_bfloat16* __restrict__ A_e,
    float* __restrict__ out_e,
    const float* __restrict__ W_s, const __hip_bfloat16* __restrict__ A_s,
    float* __restrict__ out_s,
    const int* __restrict__ offsets)
{
  extern __shared__ __align__(16) char smem[];
  float4* W0 = (float4*)smem;
  float4* W1 = W0 + 512;
  float4* A0 = W1 + 512;
  float4* A1 = A0 + 256;

  int bid = blockIdx.x;
  int xcd = bid & 7, pos = bid >> 3;
  const float* W; const short* Abase; float* outp;
  int K, bx, m_start, m_end;
  if (pos < 32){                       // shared expert (long blocks first)
    bx = pos;
    W = W_s; Abase = (const short*)A_s; outp = out_s; K = SIDIM;
    m_start = xcd*64; m_end = m_start + 64;
  } else {
    int q = xcd*240 + (pos - 32);
    int e = q >> 5; bx = q & 31;
    W = W_e + (size_t)e * HDIM * IDIM;
    Abase = (const short*)A_e; outp = out_e; K = IDIM;
    m_start = offsets[e]; m_end = offsets[e+1];
  }
  if (m_start >= m_end) return;

  int tid  = threadIdx.x;
  int lane = tid & 63;
  int wv   = tid >> 6;
  int c16 = lane & 15, kq = lane >> 4;
  int wrow = bx*64 + wv*16 + c16;
  int r    = wv*16 + c16;
  const float* WT = W + (size_t)(bx*64)*K;

  for (int m0 = m_start; m0 < m_end; m0 += 64){
    int mrem = m_end - m0;
    const short* Ar = Abase + (size_t)m0*K;
    f32x4 acc[4];
    #pragma unroll
    for (int i=0;i<4;i++) acc[i] = zero4();

    stage_w32(W0, WT, K, 0, tid);
    stage_a32(A0, Ar, K, 0, tid);

    for (int k0 = 0; k0 < K; k0 += 64){
      stage_w32(W1, WT, K, k0+32, tid);
      stage_a32(A1, Ar, K, k0+32, tid);
      VMWAIT(3); SBAR();
      {
        bf16x8 av[4];
        read_afrag32(A0, c16, kq, av);
        bf16x8 b = read_wfrag32(W0, r, kq);
        #pragma unroll
        for (int mf=0; mf<4; mf++)
          acc[mf] = mfma16(av[mf], b, acc[mf]);
      }
      SBAR();
      if (k0 + 64 < K){
        stage_w32(W0, WT, K, k0+64, tid);
        stage_a32(A0, Ar, K, k0+64, tid);
        VMWAIT(3);
      } else {
        VMWAIT(0);
      }
      SBAR();
      {
        bf16x8 av[4];
        read_afrag32(A1, c16, kq, av);
        bf16x8 b = read_wfrag32(W1, r, kq);
        #pragma unroll
        for (int mf=0; mf<4; mf++)
          acc[mf] = mfma16(av[mf], b, acc[mf]);
      }
      SBAR();
    }

    #pragma unroll
    for (int mf=0; mf<4; mf++){
      #pragma unroll
      for (int j=0;j<4;j++){
        int mrow = mf*16 + kq*4 + j;
        if (mrow < mrem)
          outp[(size_t)(m0+mrow)*HDIM + wrow] = acc[mf][j];
      }
    }
  }
}

// ---------------- final combine ----------------------------------------------
__global__ __launch_bounds__(256) void combine_kernel(
    const float* __restrict__ dslot, const float* __restrict__ shdown,
    const int* __restrict__ slot_of, const float* __restrict__ topw,
    const float* __restrict__ gates, float* __restrict__ out)
{
  int t = blockIdx.x, tid = threadIdx.x;
  int4  sl = ((const int4*)slot_of)[t];
  float4 w = ((const float4*)topw)[t];
  float sg = gates[t];
  const float* r0 = dslot + (size_t)sl.x*HDIM;
  const float* r1 = dslot + (size_t)sl.y*HDIM;
  const float* r2 = dslot + (size_t)sl.z*HDIM;
  const float* r3 = dslot + (size_t)sl.w*HDIM;
  const float* rs = shdown + (size_t)t*HDIM;
  float* o = out + (size_t)t*HDIM;
  #pragma unroll
  for (int it=0; it<HDIM/(256*4); ++it){
    int h = (tid + it*256) * 4;
    float4 a0 = *(const float4*)(r0+h);
    float4 a1 = *(const float4*)(r1+h);
    float4 a2 = *(const float4*)(r2+h);
    float4 a3 = *(const float4*)(r3+h);
    float4 as = *(const float4*)(rs+h);
    float4 r;
    r.x = w.x*a0.x + w.y*a1.x + w.z*a2.x + w.w*a3.x + sg*as.x;
    r.y = w.x*a0.y + w.y*a1.y + w.z*a2.y + w.w*a3.y + sg*as.y;
    r.z = w.x*a0.z + w.y*a1.z + w.z*a2.z + w.w*a3.z + sg*as.z;
    r.w = w.x*a0.w + w.y*a1.w + w.z*a2.w + w.w*a3.w + sg*as.w;
    *(float4*)(o+h) = r;
  }
}

extern "C" void kernel_launch(void* const* d_in, const int* in_sizes, int n_in,
                              void* d_out, int out_size, void* d_ws, size_t ws_size,
                              hipStream_t stream)
{
  const float* x         = (const float*)d_in[0];
  const float* router_w  = (const float*)d_in[1];
  const float* gate_w    = (const float*)d_in[2];
  const float* up_w      = (const float*)d_in[3];
  const float* down_w    = (const float*)d_in[4];
  const float* sh_gate_w = (const float*)d_in[5];
  const float* sh_up_w   = (const float*)d_in[6];
  const float* sh_down_w = (const float*)d_in[7];
  const float* eg_w      = (const float*)d_in[8];

  char* p = (char*)d_ws;
  auto alloc = [&](size_t bytes)->char*{
    char* r = p; p += (bytes + 255) & ~(size_t)255; return r;
  };
  int*   counts   = (int*)  alloc(NEXP*4);
  int*   fill     = (int*)  alloc(NEXP*4);
  int*   offsets  = (int*)  alloc((NEXP+1)*4);
  int*   topk_idx = (int*)  alloc(NSLOTS*4);
  float* topk_w   = (float*)alloc(NSLOTS*4);
  int*   slot_of  = (int*)  alloc(NSLOTS*4);
  float* gates    = (float*)alloc(TOKENS*4);
  __hip_bfloat16* xb    = (__hip_bfloat16*)alloc((size_t)TOKENS*HDIM*2);
  __hip_bfloat16* xg    = (__hip_bfloat16*)alloc((size_t)(NSLOTS+ROWPAD)*HDIM*2);
  __hip_bfloat16* act   = (__hip_bfloat16*)alloc((size_t)(NSLOTS+ROWPAD)*IDIM*2);
  __hip_bfloat16* shact = (__hip_bfloat16*)alloc((size_t)TOKENS*SIDIM*2);
  float* dslot  = (float*)alloc((size_t)NSLOTS*HDIM*4);
  float* shdown = (float*)alloc((size_t)TOKENS*HDIM*4);
  if ((size_t)(p - (char*)d_ws) > ws_size) return;

  hipMemsetAsync(counts, 0, NEXP*4, stream);
  hipMemsetAsync(fill,   0, NEXP*4, stream);

  router_kernel <<<TOKENS, 64, 0, stream>>>(x, router_w, eg_w, topk_idx, topk_w, gates, counts);
  prefix_kernel <<<1, 64, 0, stream>>>(counts, offsets);
  scatter_kernel<<<TOKENS, 256, 0, stream>>>(x, topk_idx, offsets, fill, slot_of, xg, xb);

  // combined gate+up: 8 XCDs x (88 shared + 165 expert) = 2024 blocks
  gateup_all<<<2024, 256, 40*1024, stream>>>(
      gate_w, up_w, xg, act,
      sh_gate_w, sh_up_w, xb, shact, offsets);

  // combined down: 8 XCDs x (32 shared + 240 expert) = 2176 blocks
  down_all<<<2176, 256, 24*1024, stream>>>(
      down_w, act, dslot,
      sh_down_w, shact, shdown, offsets);

  combine_kernel<<<TOKENS, 256, 0, stream>>>(dslot, shdown, slot_of, topk_w, gates, (float*)d_out);
}